// Round 1
// baseline (2366.176 us; speedup 1.0000x reference)
//
#include <hip/hip_runtime.h>
#include <hip/hip_bf16.h>
#include <cstdint>

#define TPB 256

// ---------------- init / stats ----------------
__global__ __launch_bounds__(TPB) void k_init(int* deg_td, int* deg_bu,
    float* pool_td, float* pool_bu, int* first, float* cnt, int N, int GH, int G) {
  int i = blockIdx.x * TPB + threadIdx.x;
  if (i < N) { deg_td[i] = 1; deg_bu[i] = 1; }
  if (i < GH) { pool_td[i] = 0.f; pool_bu[i] = 0.f; }
  if (i < G) { first[i] = 0x7fffffff; cnt[i] = 0.f; }
}

__global__ __launch_bounds__(TPB) void k_stats(const int* __restrict__ batch,
    int* first, float* cnt, int N) {
  int i = blockIdx.x * TPB + threadIdx.x;
  if (i < N) { int g = batch[i]; atomicMin(&first[g], i); atomicAdd(&cnt[g], 1.f); }
}

__global__ __launch_bounds__(TPB) void k_deg(const int* __restrict__ s,
    const int* __restrict__ d, int* deg_td, int* deg_bu, int E) {
  int e = blockIdx.x * TPB + threadIdx.x;
  if (e < E) { atomicAdd(&deg_td[d[e]], 1); atomicAdd(&deg_bu[s[e]], 1); }
}

__global__ __launch_bounds__(TPB) void k_dinv(const int* __restrict__ deg_td,
    const int* __restrict__ deg_bu, float* dinv_td, float* dinv_bu, int N) {
  int i = blockIdx.x * TPB + threadIdx.x;
  if (i < N) {
    dinv_td[i] = rsqrtf((float)deg_td[i]);
    dinv_bu[i] = rsqrtf((float)deg_bu[i]);
  }
}

// ---------------- root projection: R = relu(x[root]) @ W2[H: H+F, :] ----------------
__global__ __launch_bounds__(64) void k_root(const float* __restrict__ x,
    const int* __restrict__ first, const float* __restrict__ W2_td,
    const float* __restrict__ W2_bu, float* R_td, float* R_bu, int F, int H) {
  __shared__ float xr[256];
  int g = blockIdx.x;
  int c = blockIdx.y * 64 + threadIdx.x;
  int root = first[g];
  for (int k = threadIdx.x; k < F; k += 64) xr[k] = fmaxf(x[(size_t)root * F + k], 0.f);
  __syncthreads();
  float atd = 0.f, abu = 0.f;
  for (int k = 0; k < F; ++k) {
    float v = xr[k];
    atd += v * W2_td[(size_t)(H + k) * H + c];
    abu += v * W2_bu[(size_t)(H + k) * H + c];
  }
  R_td[(size_t)g * H + c] = atd;
  R_bu[(size_t)g * H + c] = abu;
}

// ---------------- fp32 tiled GEMM: dual-B (layer 1) ----------------
// C0 = A@B0, C1 = A@B1.  A:[M,K] B:[K,N] row-major. M%64==0, N%64==0, K%16==0.
__global__ __launch_bounds__(TPB) void gemm_dual(const float* __restrict__ A,
    const float* __restrict__ B0, const float* __restrict__ B1,
    float* __restrict__ C0, float* __restrict__ C1, int M, int K, int N) {
  __shared__ float As[16][64];
  __shared__ float Bs0[16][64];
  __shared__ float Bs1[16][64];
  const int tid = threadIdx.x;
  const int brow = blockIdx.x * 64, bcol = blockIdx.y * 64;
  const int ar = tid >> 2, ak4 = (tid & 3) << 2;
  const int bk = tid >> 4, bc4 = (tid & 15) << 2;
  const int ty = tid >> 4, tx = tid & 15;
  float acc0[4][4] = {{0}}, acc1[4][4] = {{0}};
  for (int kt = 0; kt < K; kt += 16) {
    float4 av = *(const float4*)&A[(size_t)(brow + ar) * K + kt + ak4];
    float4 b0 = *(const float4*)&B0[(size_t)(kt + bk) * N + bcol + bc4];
    float4 b1 = *(const float4*)&B1[(size_t)(kt + bk) * N + bcol + bc4];
    As[ak4 + 0][ar] = av.x; As[ak4 + 1][ar] = av.y;
    As[ak4 + 2][ar] = av.z; As[ak4 + 3][ar] = av.w;
    *(float4*)&Bs0[bk][bc4] = b0;
    *(float4*)&Bs1[bk][bc4] = b1;
    __syncthreads();
#pragma unroll
    for (int k = 0; k < 16; ++k) {
      float a_[4], c0_[4], c1_[4];
#pragma unroll
      for (int i = 0; i < 4; ++i) a_[i] = As[k][ty * 4 + i];
#pragma unroll
      for (int j = 0; j < 4; ++j) { c0_[j] = Bs0[k][tx * 4 + j]; c1_[j] = Bs1[k][tx * 4 + j]; }
#pragma unroll
      for (int i = 0; i < 4; ++i)
#pragma unroll
        for (int j = 0; j < 4; ++j) {
          acc0[i][j] += a_[i] * c0_[j];
          acc1[i][j] += a_[i] * c1_[j];
        }
    }
    __syncthreads();
  }
#pragma unroll
  for (int i = 0; i < 4; ++i)
#pragma unroll
    for (int j = 0; j < 4; ++j) {
      int r = brow + ty * 4 + i, c = bcol + tx * 4 + j;
      C0[(size_t)r * N + c] = acc0[i][j];
      C1[(size_t)r * N + c] = acc1[i][j];
    }
}

// ---------------- fp32 tiled GEMM: layer 2 (relu on A, + per-graph R broadcast) ----------------
__global__ __launch_bounds__(TPB) void gemm_l2(const float* __restrict__ A,
    const float* __restrict__ B, float* __restrict__ Cc,
    const float* __restrict__ Rb, const int* __restrict__ batch, int M, int K, int N) {
  __shared__ float As[16][64];
  __shared__ float Bs[16][64];
  const int tid = threadIdx.x;
  const int brow = blockIdx.x * 64, bcol = blockIdx.y * 64;
  const int ar = tid >> 2, ak4 = (tid & 3) << 2;
  const int bk = tid >> 4, bc4 = (tid & 15) << 2;
  const int ty = tid >> 4, tx = tid & 15;
  float acc[4][4] = {{0}};
  for (int kt = 0; kt < K; kt += 16) {
    float4 av = *(const float4*)&A[(size_t)(brow + ar) * K + kt + ak4];
    av.x = fmaxf(av.x, 0.f); av.y = fmaxf(av.y, 0.f);
    av.z = fmaxf(av.z, 0.f); av.w = fmaxf(av.w, 0.f);
    float4 bv = *(const float4*)&B[(size_t)(kt + bk) * N + bcol + bc4];
    As[ak4 + 0][ar] = av.x; As[ak4 + 1][ar] = av.y;
    As[ak4 + 2][ar] = av.z; As[ak4 + 3][ar] = av.w;
    *(float4*)&Bs[bk][bc4] = bv;
    __syncthreads();
#pragma unroll
    for (int k = 0; k < 16; ++k) {
      float a_[4], b_[4];
#pragma unroll
      for (int i = 0; i < 4; ++i) a_[i] = As[k][ty * 4 + i];
#pragma unroll
      for (int j = 0; j < 4; ++j) b_[j] = Bs[k][tx * 4 + j];
#pragma unroll
      for (int i = 0; i < 4; ++i)
#pragma unroll
        for (int j = 0; j < 4; ++j) acc[i][j] += a_[i] * b_[j];
    }
    __syncthreads();
  }
#pragma unroll
  for (int i = 0; i < 4; ++i) {
    int r = brow + ty * 4 + i;
    int g = batch[r];
#pragma unroll
    for (int j = 0; j < 4; ++j) {
      int c = bcol + tx * 4 + j;
      Cc[(size_t)r * N + c] = acc[i][j] + Rb[(size_t)g * N + c];
    }
  }
}

// ---------------- conv: self-loop init  y = xw*dinv^2 + bias ----------------
__global__ __launch_bounds__(TPB) void k_conv_init(const float* __restrict__ xw,
    float* __restrict__ y, const float* __restrict__ dinv,
    const float* __restrict__ bias, int N, int H) {
  int idx = blockIdx.x * TPB + threadIdx.x;
  int tot = N * (H >> 2);
  if (idx >= tot) return;
  int i = idx / (H >> 2);
  int c4 = (idx - i * (H >> 2)) << 2;
  float di = dinv[i];
  float s = di * di;
  float4 v = *(const float4*)&xw[(size_t)i * H + c4];
  float4 b = *(const float4*)&bias[c4];
  float4 o;
  o.x = v.x * s + b.x; o.y = v.y * s + b.y; o.z = v.z * s + b.z; o.w = v.w * s + b.w;
  *(float4*)&y[(size_t)i * H + c4] = o;
}

// ---------------- conv: edge scatter  y[d] += xw[s]*dinv[s]*dinv[d] ----------------
__global__ void k_conv_edges(const float* __restrict__ xw, float* __restrict__ y,
    const int* __restrict__ s, const int* __restrict__ d,
    const float* __restrict__ dinv, int E, int H) {
  int e = blockIdx.x;
  int c = threadIdx.x;
  int si = s[e], di = d[e];
  float nrm = dinv[si] * dinv[di];
  atomicAdd(&y[(size_t)di * H + c], xw[(size_t)si * H + c] * nrm);
}

// ---------------- pool: pool[g] += relu(y[i]), batched flush ----------------
__global__ __launch_bounds__(TPB) void k_pool(const float* __restrict__ y,
    float* __restrict__ pool, const int* __restrict__ batch, int N, int H) {
  int c = threadIdx.x;  // H == 256
  int n0 = blockIdx.x * 256;
  int n1 = min(n0 + 256, N);
  float acc = 0.f;
  int cur = batch[n0];
  for (int i = n0; i < n1; ++i) {
    int g = batch[i];
    if (g != cur) { atomicAdd(&pool[(size_t)cur * H + c], acc); acc = 0.f; cur = g; }
    acc += fmaxf(y[(size_t)i * H + c], 0.f);
  }
  atomicAdd(&pool[(size_t)cur * H + c], acc);
}

// ---------------- head: logits = [pool_td, pool_bu]/cnt @ Wl + bl ; log_softmax ----------------
__global__ __launch_bounds__(128) void k_head(const float* __restrict__ pool_td,
    const float* __restrict__ pool_bu, const float* __restrict__ cnt,
    const float* __restrict__ Wl, const float* __restrict__ bl,
    float* __restrict__ out, int H, int C) {
  int g = blockIdx.x;
  int t = threadIdx.x;
  float inv = 1.f / cnt[g];
  float acc[8];
  for (int c = 0; c < C; ++c) acc[c] = 0.f;
  int twoH = 2 * H;
  for (int d0 = t; d0 < twoH; d0 += 128) {
    float v = (d0 < H ? pool_td[(size_t)g * H + d0] : pool_bu[(size_t)g * H + d0 - H]) * inv;
    for (int c = 0; c < C; ++c) acc[c] += v * Wl[(size_t)d0 * C + c];
  }
  __shared__ float red[128 * 8];
  for (int c = 0; c < C; ++c) red[t * C + c] = acc[c];
  __syncthreads();
  for (int off = 64; off > 0; off >>= 1) {
    if (t < off)
      for (int c = 0; c < C; ++c) red[t * C + c] += red[(t + off) * C + c];
    __syncthreads();
  }
  if (t == 0) {
    float l[8];
    float m = -1e30f;
    for (int c = 0; c < C; ++c) { l[c] = red[c] + bl[c]; m = fmaxf(m, l[c]); }
    float ssum = 0.f;
    for (int c = 0; c < C; ++c) ssum += expf(l[c] - m);
    float ls = logf(ssum);
    for (int c = 0; c < C; ++c) out[(size_t)g * C + c] = l[c] - m - ls;
  }
}

extern "C" void kernel_launch(void* const* d_in, const int* in_sizes, int n_in,
                              void* d_out, int out_size, void* d_ws, size_t ws_size,
                              hipStream_t stream) {
  const float* x     = (const float*)d_in[0];
  const int*   ei    = (const int*)d_in[1];
  const int*   batch = (const int*)d_in[2];
  const float* W1_td = (const float*)d_in[4];
  const float* b1_td = (const float*)d_in[5];
  const float* W1_bu = (const float*)d_in[6];
  const float* b1_bu = (const float*)d_in[7];
  const float* W2_td = (const float*)d_in[8];
  const float* b2_td = (const float*)d_in[9];
  const float* W2_bu = (const float*)d_in[10];
  const float* b2_bu = (const float*)d_in[11];
  const float* Wl    = (const float*)d_in[12];
  const float* bl    = (const float*)d_in[13];
  float* out = (float*)d_out;

  const int N = in_sizes[2];
  const int H = in_sizes[5];
  const int F = in_sizes[0] / N;
  const int E = in_sizes[1] / 2;
  const int C = in_sizes[13];
  const int G = out_size / C;

  const int* srcp = ei;
  const int* dstp = ei + E;

  const size_t NH = (size_t)N * H;
  float* buf0    = (float*)d_ws;         // N*H
  float* buf1    = buf0 + NH;            // N*H
  float* buf2    = buf1 + NH;            // N*H
  float* dinv_td = buf2 + NH;            // N
  float* dinv_bu = dinv_td + N;          // N
  float* R_td    = dinv_bu + N;          // G*H
  float* R_bu    = R_td + (size_t)G * H; // G*H
  float* pool_td = R_bu + (size_t)G * H; // G*H
  float* pool_bu = pool_td + (size_t)G * H;
  float* cnt     = pool_bu + (size_t)G * H; // G
  int* deg_td = (int*)(cnt + G);         // N
  int* deg_bu = deg_td + N;              // N
  int* first  = deg_bu + N;              // G
  size_t need = (size_t)((char*)(first + G) - (char*)d_ws);
  if (need > ws_size) return;  // workspace too small; fail loudly via validation

  const int nbN = (N + TPB - 1) / TPB;
  const int nbE = (E + TPB - 1) / TPB;
  const int GH = G * H;

  k_init<<<nbN, TPB, 0, stream>>>(deg_td, deg_bu, pool_td, pool_bu, first, cnt, N, GH, G);
  k_stats<<<nbN, TPB, 0, stream>>>(batch, first, cnt, N);
  k_deg<<<nbE, TPB, 0, stream>>>(srcp, dstp, deg_td, deg_bu, E);
  k_dinv<<<nbN, TPB, 0, stream>>>(deg_td, deg_bu, dinv_td, dinv_bu, N);
  k_root<<<dim3(G, H / 64), 64, 0, stream>>>(x, first, W2_td, W2_bu, R_td, R_bu, F, H);

  // ---- layer 1: xw_td -> buf0, xw_bu -> buf1 (single pass over x) ----
  gemm_dual<<<dim3(N / 64, H / 64), TPB, 0, stream>>>(x, W1_td, W1_bu, buf0, buf1, N, F, H);

  const int nbNH4 = (int)((NH / 4 + TPB - 1) / TPB);
  // td conv:  buf0 -> buf2  (td1)
  k_conv_init<<<nbNH4, TPB, 0, stream>>>(buf0, buf2, dinv_td, b1_td, N, H);
  k_conv_edges<<<E, H, 0, stream>>>(buf0, buf2, srcp, dstp, dinv_td, E, H);
  // bu conv:  buf1 -> buf0  (bu1)
  k_conv_init<<<nbNH4, TPB, 0, stream>>>(buf1, buf0, dinv_bu, b1_bu, N, H);
  k_conv_edges<<<E, H, 0, stream>>>(buf1, buf0, dstp, srcp, dinv_bu, E, H);

  // ---- layer 2 td: xw2_td = relu(buf2)@W2_td[:H] + R_td[g]  -> buf1; conv -> buf2 ----
  gemm_l2<<<dim3(N / 64, H / 64), TPB, 0, stream>>>(buf2, W2_td, buf1, R_td, batch, N, H, H);
  k_conv_init<<<nbNH4, TPB, 0, stream>>>(buf1, buf2, dinv_td, b2_td, N, H);
  k_conv_edges<<<E, H, 0, stream>>>(buf1, buf2, srcp, dstp, dinv_td, E, H);
  k_pool<<<(N + 255) / 256, TPB, 0, stream>>>(buf2, pool_td, batch, N, H);

  // ---- layer 2 bu: xw2_bu = relu(buf0)@W2_bu[:H] + R_bu[g]  -> buf1; conv -> buf0 ----
  gemm_l2<<<dim3(N / 64, H / 64), TPB, 0, stream>>>(buf0, W2_bu, buf1, R_bu, batch, N, H, H);
  k_conv_init<<<nbNH4, TPB, 0, stream>>>(buf1, buf0, dinv_bu, b2_bu, N, H);
  k_conv_edges<<<E, H, 0, stream>>>(buf1, buf0, dstp, srcp, dinv_bu, E, H);
  k_pool<<<(N + 255) / 256, TPB, 0, stream>>>(buf0, pool_bu, batch, N, H);

  // ---- head ----
  k_head<<<G, 128, 0, stream>>>(pool_td, pool_bu, cnt, Wl, bl, out, H, C);
}